// Round 9
// baseline (155.659 us; speedup 1.0000x reference)
//
#include <hip/hip_runtime.h>
#include <hip/hip_bf16.h>
#include <stdint.h>

typedef unsigned short u16;
typedef __attribute__((ext_vector_type(8))) unsigned short u16x8;
typedef __attribute__((ext_vector_type(4))) unsigned short u16x4;
typedef __attribute__((ext_vector_type(8))) __bf16 bf16x8;
typedef __attribute__((ext_vector_type(4))) float f32x4;
typedef __attribute__((ext_vector_type(16))) float f32x16;

#define LOG2E 1.44269504088896340736f

#if defined(__has_builtin)
#if __has_builtin(__builtin_amdgcn_exp2f)
#define EXP2(x) __builtin_amdgcn_exp2f(x)
#endif
#endif
#ifndef EXP2
#define EXP2(x) exp2f(x)
#endif

// ---------- helpers ----------
__device__ __forceinline__ f32x4 mfma16(u16x8 a, u16x8 b, f32x4 c) {
  return __builtin_amdgcn_mfma_f32_16x16x32_bf16(
      __builtin_bit_cast(bf16x8, a), __builtin_bit_cast(bf16x8, b), c, 0, 0, 0);
}

__device__ __forceinline__ f32x16 mfma32(u16x8 a, u16x8 b, f32x16 c) {
  return __builtin_amdgcn_mfma_f32_32x32x16_bf16(
      __builtin_bit_cast(bf16x8, a), __builtin_bit_cast(bf16x8, b), c, 0, 0, 0);
}

__device__ __forceinline__ u16 f2bf(float f) {
  unsigned u = __builtin_bit_cast(unsigned, f);
  return (u16)((u + 0x7fffu + ((u >> 16) & 1u)) >> 16);
}

__device__ __forceinline__ unsigned cvtpk(float a, float b) {
  unsigned r;
  asm volatile("v_cvt_pk_bf16_f32 %0, %1, %2" : "=v"(r) : "v"(a), "v"(b));
  return r;
}

// v_permlane32_swap_b32: a[32..63] <-> b[0..31]
__device__ __forceinline__ void pswap(unsigned& a, unsigned& b) {
  asm volatile("v_permlane32_swap_b32 %0, %1" : "+v"(a), "+v"(b));
}

__device__ __forceinline__ void gload_lds16(const void* g, void* l) {
  __builtin_amdgcn_global_load_lds(
      (__attribute__((address_space(1))) void*)const_cast<void*>(g),
      (__attribute__((address_space(3))) void*)l, 16, 0, 0);
}

template<int N> __device__ __forceinline__ void vmwait() {
  asm volatile("s_waitcnt vmcnt(%0)" :: "n"(N) : "memory");
  __builtin_amdgcn_sched_barrier(0);
}

#define SWZ(row, colbyte) ((((row) * 128) + (colbyte)) ^ (((row) & 7) << 4))

// ---------- fp32 -> bf16 casts ----------
__global__ void cast_f32_bf16(const float* __restrict__ src, u16* __restrict__ dst, int n4) {
  int i = blockIdx.x * blockDim.x + threadIdx.x;
  if (i < n4) {
    f32x4 v = ((const f32x4*)src)[i];
    u16x4 o;
    o[0] = f2bf(v[0]); o[1] = f2bf(v[1]); o[2] = f2bf(v[2]); o[3] = f2bf(v[3]);
    ((u16x4*)dst)[i] = o;
  }
}

__global__ void cast3_f32_bf16(const float* __restrict__ s0, const float* __restrict__ s1,
                               const float* __restrict__ s2, u16* __restrict__ dst) {
  const int seg = blockIdx.x >> 10;
  const int i = (blockIdx.x & 1023) * blockDim.x + threadIdx.x;
  const float* src = (seg == 0) ? s0 : ((seg == 1) ? s1 : s2);
  f32x4 v = ((const f32x4*)src)[i];
  u16x4 o;
  o[0] = f2bf(v[0]); o[1] = f2bf(v[1]); o[2] = f2bf(v[2]); o[3] = f2bf(v[3]);
  ((u16x4*)(dst + (size_t)seg * 1048576))[i] = o;
}

// ---------- fused QKV GEMM (3-buf, depth-2 prefetch, counted vmcnt) ----------
__global__ __launch_bounds__(256) void gemm_qkv(
    const u16* __restrict__ A, const u16* __restrict__ Bm,
    const float* __restrict__ bq, const float* __restrict__ bk, const float* __restrict__ bv,
    u16* __restrict__ Qb, u16* __restrict__ Kb, u16* __restrict__ VTb) {
  __shared__ __align__(16) u16 Asm[3][4096];
  __shared__ __align__(16) u16 Bsm[3][4096];
  const int tid = threadIdx.x;
  const int wave = tid >> 6, lane = tid & 63;
  const int lq = lane & 15, lg = lane >> 4;
  const int wr = wave >> 1, wc = wave & 1;
  const int lin = blockIdx.y * 24 + blockIdx.x;
  const int wg = (lin & 7) * 96 + (lin >> 3);
  const int m0 = (wg / 24) * 128, n0 = (wg % 24) * 128;

  f32x4 zero = {0.f, 0.f, 0.f, 0.f};
  f32x4 acc[4][4];
#pragma unroll
  for (int mi = 0; mi < 4; ++mi)
#pragma unroll
    for (int ni = 0; ni < 4; ++ni) acc[mi][ni] = zero;

  auto stage = [&](int kt, int buf) {
    const int k0 = kt * 32;
#pragma unroll
    for (int c = 0; c < 2; ++c) {
      const int idx = wave * 2 + c;
      const u16* ga = A + (size_t)(m0 + idx * 16 + (lane >> 2)) * 1024 + k0 + (lane & 3) * 8;
      gload_lds16(ga, (char*)&Asm[buf][0] + idx * 1024);
      const u16* gb = Bm + (size_t)(n0 + idx * 16 + (lane >> 2)) * 1024 + k0 + (lane & 3) * 8;
      gload_lds16(gb, (char*)&Bsm[buf][0] + idx * 1024);
    }
  };

  stage(0, 0);
  stage(1, 1);
  for (int kt = 0; kt < 32; ++kt) {
    if (kt < 31) vmwait<4>(); else vmwait<0>();
    __builtin_amdgcn_s_barrier();
    if (kt + 2 < 32) stage(kt + 2, (kt + 2) % 3);
    const int cur = kt % 3;

    __builtin_amdgcn_s_setprio(1);
    u16x8 af[4], bfr[4];
#pragma unroll
    for (int mi = 0; mi < 4; ++mi)
      af[mi] = *(const u16x8*)&Asm[cur][(wr * 64 + mi * 16 + lq) * 32 + lg * 8];
#pragma unroll
    for (int ni = 0; ni < 4; ++ni)
      bfr[ni] = *(const u16x8*)&Bsm[cur][(wc * 64 + ni * 16 + lq) * 32 + lg * 8];
#pragma unroll
    for (int mi = 0; mi < 4; ++mi)
#pragma unroll
      for (int ni = 0; ni < 4; ++ni)
        acc[mi][ni] = mfma16(af[mi], bfr[ni], acc[mi][ni]);
    __builtin_amdgcn_s_setprio(0);
  }

  const int which = n0 >> 10;
  const float* bias = (which == 0) ? bq : ((which == 1) ? bk : bv);
  const float scl = (which == 0) ? (0.125f * LOG2E) : 1.0f;
#pragma unroll
  for (int mi = 0; mi < 4; ++mi) {
    const int m = m0 + wr * 64 + mi * 16 + lg * 4;
    const int bb = m >> 11;
    const int s = m & 2047;
#pragma unroll
    for (int ni = 0; ni < 4; ++ni) {
      const int n = n0 + wc * 64 + ni * 16 + lq;
      const int d = n & 1023;
      const int h = d >> 6, dh = d & 63;
      const float bi = bias[d];
#pragma unroll
      for (int r = 0; r < 4; ++r) {
        float v = (acc[mi][ni][r] + bi) * scl;
        if (which == 2)
          VTb[(((size_t)bb * 16 + h) * 64 + dh) * 2048 + (size_t)(s + r)] = f2bf(v);
        else {
          u16* dst = (which == 0) ? Qb : Kb;
          dst[(((size_t)bb * 16 + h) * 2048 + (size_t)(s + r)) * 64 + dh] = f2bf(v);
        }
      }
    }
  }
}

// ---------- attention: 32x32 MFMA, in-register P via cvtpk+permlane32_swap ----------
// 512 thr = 8 waves, 32 q/wave (q in lane&31); grid 256 = 1 block/CU.
// Swapped QK^T D[k][q]; P transposed to PV A-frags entirely in registers.
__global__ __launch_bounds__(512) void attn_main(
    const u16* __restrict__ Qb, const u16* __restrict__ Kb, const u16* __restrict__ VTb,
    const float* __restrict__ maskg, float* __restrict__ out_ctx, float* __restrict__ winv) {
  __shared__ __align__(16) u16 Kl[3][4096];   // 24 KB
  __shared__ __align__(16) u16 VTl[3][4096];  // 24 KB
  __shared__ float sml[256];                  // 1 KB: per-wave 32 x 1/l

  const int tid = threadIdx.x;
  const int w = tid >> 6, lane = tid & 63;
  const int l31 = lane & 31, h = lane >> 5;
  // XCD swizzle: 256 blocks -> 4 consecutive bh per XCD
  const int bid = (blockIdx.x & 7) * 32 + (blockIdx.x >> 3);
  const int qt = bid & 7, bh = bid >> 3;
  const int b = bh >> 4, hh = bh & 15;
  const int qw = qt * 256 + w * 32;  // wave's 32 q rows

  // Q frags: lane holds Q[qw+l31][dh = 16dq + 8h + j]
  const u16* qp = Qb + ((size_t)bh * 2048 + qw + l31) * 64 + h * 8;
  u16x8 qa[4];
#pragma unroll
  for (int dq = 0; dq < 4; ++dq) qa[dq] = *(const u16x8*)(qp + dq * 16);

  const char* Kbase = (const char*)(Kb + (size_t)bh * 2048 * 64);
  const char* VTbase = (const char*)(VTb + (size_t)bh * 64 * 2048);
  const float* mbase = maskg + b * 2048;

  // staging: 512 x 16B chunks per 8KB tile, 1/thread; pre-swizzled source
  const int srow = tid >> 3;
  const int scol = ((tid & 7) * 16) ^ ((srow & 7) << 4);
  auto stageK = [&](int kt, int buf) {
    gload_lds16(Kbase + (size_t)(kt * 64 + srow) * 128 + scol, (char*)&Kl[buf][0] + w * 1024);
  };
  auto stageVT = [&](int kt, int buf) {
    gload_lds16(VTbase + (size_t)srow * 4096 + (size_t)kt * 128 + scol, (char*)&VTl[buf][0] + w * 1024);
  };

  f32x16 accpv[2];
#pragma unroll
  for (int db = 0; db < 2; ++db)
#pragma unroll
    for (int r = 0; r < 16; ++r) accpv[db][r] = 0.f;
  float l_l = 0.f;

  stageK(0, 0); stageVT(0, 0);
  stageK(1, 1); stageVT(1, 1);
  for (int kt = 0; kt < 32; ++kt) {
    if (kt < 31) vmwait<2>(); else vmwait<0>();
    __builtin_amdgcn_s_barrier();
    const char* Kt = (const char*)&Kl[kt % 3][0];
    const char* Vt = (const char*)&VTl[kt % 3][0];

    __builtin_amdgcn_s_setprio(1);
#pragma unroll
    for (int kb = 0; kb < 2; ++kb) {
      // QK^T: S[k = kb*32 + (r&3)+8(r>>2)+4h][q = l31]
      f32x16 s;
#pragma unroll
      for (int r = 0; r < 16; ++r) s[r] = 0.f;
#pragma unroll
      for (int dq = 0; dq < 4; ++dq) {
        const u16x8 ka = *(const u16x8*)(Kt + SWZ(kb * 32 + l31, dq * 32 + h * 16));
        s = mfma32(ka, qa[dq], s);
      }
      // mask + exp2 (Q pre-scaled by 0.125*log2e)
      float p[16];
#pragma unroll
      for (int g = 0; g < 4; ++g) {
        const f32x4 mv = *(const f32x4*)(mbase + kt * 64 + kb * 32 + g * 8 + h * 4);
#pragma unroll
        for (int j = 0; j < 4; ++j)
          p[g * 4 + j] = EXP2(fmaf(mv[j], LOG2E, s[g * 4 + j]));
      }
      l_l += ((p[0] + p[1]) + (p[2] + p[3])) + ((p[4] + p[5]) + (p[6] + p[7])) +
             ((p[8] + p[9]) + (p[10] + p[11])) + ((p[12] + p[13]) + (p[14] + p[15]));
      // P -> PV A-frags: pairs (k,k+1) packed, then swap lane-halves.
      unsigned a01 = cvtpk(p[0], p[1]), a23 = cvtpk(p[2], p[3]);
      unsigned a45 = cvtpk(p[4], p[5]), a67 = cvtpk(p[6], p[7]);
      unsigned b01 = cvtpk(p[8], p[9]), b23 = cvtpk(p[10], p[11]);
      unsigned b45 = cvtpk(p[12], p[13]), b67 = cvtpk(p[14], p[15]);
      pswap(a01, a45); pswap(a23, a67);  // frag ks2=0: k = kb*32 + [0,16)
      pswap(b01, b45); pswap(b23, b67);  // frag ks2=1: k = kb*32 + [16,32)
      uint4 f1 = {a01, a23, a45, a67};
      uint4 f2 = {b01, b23, b45, b67};
      u16x8 pf[2] = {__builtin_bit_cast(u16x8, f1), __builtin_bit_cast(u16x8, f2)};
      // PV: ctx[q][dh] += P[q][k] * VT[dh][k]
#pragma unroll
      for (int ks2 = 0; ks2 < 2; ++ks2) {
#pragma unroll
        for (int db = 0; db < 2; ++db) {
          const u16x8 vt = *(const u16x8*)(Vt + SWZ(db * 32 + l31, kb * 64 + ks2 * 32 + h * 16));
          accpv[db] = mfma32(pf[ks2], vt, accpv[db]);
        }
      }
    }
    __builtin_amdgcn_s_setprio(0);
    __builtin_amdgcn_sched_barrier(0);
    if (kt + 2 < 32) {  // stage AFTER compute: in-compute mask loads only drain old stages
      stageK(kt + 2, (kt + 2) % 3);
      stageVT(kt + 2, (kt + 2) % 3);
    }
  }

  // l: sum the two lane-halves (distinct k each), then normalize
  l_l += __shfl_xor(l_l, 32);
  const float il = 1.0f / l_l;
  if (h == 0) {
    winv[bh * 2048 + qw + l31] = il;
    sml[w * 32 + l31] = il;
  }
  __syncthreads();
  f32x4 il4[4];
#pragma unroll
  for (int g = 0; g < 4; ++g) il4[g] = *(const f32x4*)&sml[w * 32 + g * 8 + h * 4];

  // ctx: lane holds D[q = (r&3)+8(r>>2)+4h][dh = db*32 + l31]
#pragma unroll
  for (int db = 0; db < 2; ++db) {
#pragma unroll
    for (int r = 0; r < 16; ++r) {
      const int q = qw + (r & 3) + (r >> 2) * 8 + h * 4;
      out_ctx[(size_t)(b * 2048 + q) * 1024 + hh * 64 + db * 32 + l31] =
          accpv[db][r] * il4[r >> 2][r & 3];
    }
  }
}

// ---------- colsum: c_k = sum_q exp2(s + mask*L) * winv_q ----------
__global__ __launch_bounds__(256) void colsum_kernel(
    const u16* __restrict__ Qb, const u16* __restrict__ Kb,
    const float* __restrict__ maskg, const float* __restrict__ winv,
    float* __restrict__ out_cs) {
  __shared__ __align__(16) u16 Ql[3][4096];

  const int tid = threadIdx.x;
  const int w = tid >> 6, lane = tid & 63;
  const int lq = lane & 15, lg = lane >> 4;
  const int bid = (blockIdx.x & 7) * 64 + (blockIdx.x >> 3);
  const int ktile = bid & 15, bh = bid >> 4;
  const int b = bh >> 4;
  const int kbase = ktile * 128 + w * 32;

  const u16* kp0 = Kb + ((size_t)bh * 2048 + kbase + lq) * 64 + lg * 8;
  const u16* kp1 = kp0 + 16 * 64;
  const u16x8 kb00 = *(const u16x8*)kp0, kb01 = *(const u16x8*)(kp0 + 32);
  const u16x8 kb10 = *(const u16x8*)kp1, kb11 = *(const u16x8*)(kp1 + 32);
  const float mvl0 = maskg[b * 2048 + kbase + lq] * LOG2E;
  const float mvl1 = maskg[b * 2048 + kbase + 16 + lq] * LOG2E;
  const float* wbase = winv + bh * 2048;
  const char* Qbase = (const char*)(Qb + (size_t)bh * 2048 * 64);

  const int r0 = tid >> 3;
  const int scol = ((tid & 7) * 16) ^ ((r0 & 7) << 4);
  auto stageQ = [&](int qt, int buf) {
    const char* src = Qbase + (size_t)(qt * 64) * 128;
    char* d = (char*)&Ql[buf][0] + w * 1024;
    gload_lds16(src + (size_t)r0 * 128 + scol, d);
    gload_lds16(src + (size_t)(r0 + 32) * 128 + scol, d + 4096);
  };

  float c0 = 0.f, c1 = 0.f;
  stageQ(0, 0);
  stageQ(1, 1);
  for (int qt = 0; qt < 32; ++qt) {
    if (qt < 31) vmwait<2>(); else vmwait<0>();
    __builtin_amdgcn_s_barrier();
    const char* Qt = (const char*)&Ql[qt % 3][0];
    __builtin_amdgcn_s_setprio(1);
#pragma unroll
    for (int chunk = 0; chunk < 4; ++chunk) {
      const u16x8 qf0 = *(const u16x8*)(Qt + SWZ(chunk * 16 + lq, lg * 16));
      const u16x8 qf1 = *(const u16x8*)(Qt + SWZ(chunk * 16 + lq, 64 + lg * 16));
      f32x4 z = {0.f, 0.f, 0.f, 0.f};
      f32x4 s0 = mfma16(qf0, kb00, z);
      s0 = mfma16(qf1, kb01, s0);
      f32x4 s1 = mfma16(qf0, kb10, z);
      s1 = mfma16(qf1, kb11, s1);
      const f32x4 wv = *(const f32x4*)(wbase + qt * 64 + chunk * 16 + lg * 4);
#pragma unroll
      for (int r = 0; r < 4; ++r) {
        c0 += EXP2(s0[r] + mvl0) * wv[r];
        c1 += EXP2(s1[r] + mvl1) * wv[r];
      }
    }
    __builtin_amdgcn_s_setprio(0);
    __builtin_amdgcn_sched_barrier(0);
    if (qt + 2 < 32) stageQ(qt + 2, (qt + 2) % 3);  // stage after compute
  }
  c0 += __shfl_xor(c0, 16); c0 += __shfl_xor(c0, 32);
  c1 += __shfl_xor(c1, 16); c1 += __shfl_xor(c1, 32);
  if (lg == 0) {
    atomicAdd(&out_cs[b * 2048 + kbase + lq], c0);
    atomicAdd(&out_cs[b * 2048 + kbase + 16 + lq], c1);
  }
}

// ---------- launch ----------
extern "C" void kernel_launch(void* const* d_in, const int* in_sizes, int n_in,
                              void* d_out, int out_size, void* d_ws, size_t ws_size,
                              hipStream_t stream) {
  (void)in_sizes; (void)n_in; (void)out_size; (void)ws_size;
  const float* X    = (const float*)d_in[0];
  const float* mask = (const float*)d_in[1];
  const float* Wq   = (const float*)d_in[2];
  const float* bq   = (const float*)d_in[3];
  const float* Wk   = (const float*)d_in[4];
  const float* bk   = (const float*)d_in[5];
  const float* Wv   = (const float*)d_in[6];
  const float* bv   = (const float*)d_in[7];
  float* out = (float*)d_out;

  char* ws = (char*)d_ws;
  u16* Xb   = (u16*)(ws);
  u16* Wcat = (u16*)(ws + 8388608);
  u16* Qb   = (u16*)(ws + 14680064);
  u16* Kb   = (u16*)(ws + 23068672);
  u16* VTb  = (u16*)(ws + 31457280);
  float* winv = (float*)(ws + 39845888);

  cast_f32_bf16<<<4096, 256, 0, stream>>>(X, Xb, 1048576);
  cast3_f32_bf16<<<3072, 256, 0, stream>>>(Wq, Wk, Wv, Wcat);

  hipMemsetAsync(out + 4194304, 0, 4096 * sizeof(float), stream);

  gemm_qkv<<<dim3(24, 32), 256, 0, stream>>>(Xb, Wcat, bq, bk, bv, Qb, Kb, VTb);

  attn_main<<<256, 512, 0, stream>>>(Qb, Kb, VTb, mask, out, winv);
  colsum_kernel<<<512, 256, 0, stream>>>(Qb, Kb, mask, winv, out + 4194304);
}